// Round 1
// baseline (236.917 us; speedup 1.0000x reference)
//
#include <hip/hip_runtime.h>
#include <math.h>

namespace {
constexpr int N  = 32;
constexpr int NB = 2048;
constexpr int T  = 1024;
constexpr float DT_  = 0.1f;
constexpr float RMIN = 1.0e5f, RMAX = 1.0e7f;
constexpr float CMIN = 1.0e-7f, CMAX = 1.0e-4f;
constexpr int BLOCK  = 256;
constexpr int CHUNK  = 16;           // floats processed per pipelined iteration
constexpr int NCHUNK = T / CHUNK;    // 64
}

__global__ void __launch_bounds__(BLOCK)
lf_scan(const float* __restrict__ x,
        const float* __restrict__ Rp,
        const float* __restrict__ Cp,
        const float* __restrict__ noise_R,
        const float* __restrict__ noise_C,
        const float* __restrict__ mu,
        const float* __restrict__ memory0,
        float* __restrict__ out)
{
    __shared__ float beta_s[T];
    const int tid = threadIdx.x;
    const int n   = blockIdx.y;

    // ---- per-block beta computation (t = 0..T-1 for this n) ----
    const float R_true = (RMAX - RMIN) / (1.0f + expf(-Rp[0])) + RMIN;
    const float C_true = (CMAX - CMIN) / (1.0f + expf(-Cp[0])) + CMIN;
    for (int i = tid; i < T; i += BLOCK) {
        const int idx = i * N + n;                       // (T, N, 1) layout
        const float rc = mu[idx] * (R_true * noise_R[idx]) * (C_true * noise_C[idx]);
        beta_s[i] = rc / (rc + DT_);
    }
    __syncthreads();

    // ---- sequential scan, one thread per (n, nb) sequence ----
    const int nb = blockIdx.x * BLOCK + tid;
    const size_t base = ((size_t)n * NB + (size_t)nb) * (size_t)T;
    const float4* __restrict__ xv = reinterpret_cast<const float4*>(x + base);
    float4*       __restrict__ ov = reinterpret_cast<float4*>(out + base);

    float mem = memory0[n * NB + nb];

    float4 c0 = xv[0], c1 = xv[1], c2 = xv[2], c3 = xv[3];

    auto do_chunk = [&](int c, float4 v0, float4 v1, float4 v2, float4 v3) {
        const int t = c * CHUNK;
        float4 o;
        // out[t] records PRE-update memory; update m = b*(m - x) + x
        o.x = mem; mem = fmaf(beta_s[t +  0], mem - v0.x, v0.x);
        o.y = mem; mem = fmaf(beta_s[t +  1], mem - v0.y, v0.y);
        o.z = mem; mem = fmaf(beta_s[t +  2], mem - v0.z, v0.z);
        o.w = mem; mem = fmaf(beta_s[t +  3], mem - v0.w, v0.w);
        ov[4 * c + 0] = o;
        o.x = mem; mem = fmaf(beta_s[t +  4], mem - v1.x, v1.x);
        o.y = mem; mem = fmaf(beta_s[t +  5], mem - v1.y, v1.y);
        o.z = mem; mem = fmaf(beta_s[t +  6], mem - v1.z, v1.z);
        o.w = mem; mem = fmaf(beta_s[t +  7], mem - v1.w, v1.w);
        ov[4 * c + 1] = o;
        o.x = mem; mem = fmaf(beta_s[t +  8], mem - v2.x, v2.x);
        o.y = mem; mem = fmaf(beta_s[t +  9], mem - v2.y, v2.y);
        o.z = mem; mem = fmaf(beta_s[t + 10], mem - v2.z, v2.z);
        o.w = mem; mem = fmaf(beta_s[t + 11], mem - v2.w, v2.w);
        ov[4 * c + 2] = o;
        o.x = mem; mem = fmaf(beta_s[t + 12], mem - v3.x, v3.x);
        o.y = mem; mem = fmaf(beta_s[t + 13], mem - v3.y, v3.y);
        o.z = mem; mem = fmaf(beta_s[t + 14], mem - v3.z, v3.z);
        o.w = mem; mem = fmaf(beta_s[t + 15], mem - v3.w, v3.w);
        ov[4 * c + 3] = o;
    };

    // software pipeline: prefetch next 64 B chunk while computing current
    for (int c = 0; c < NCHUNK - 1; ++c) {
        float4 n0 = xv[4 * c + 4];
        float4 n1 = xv[4 * c + 5];
        float4 n2 = xv[4 * c + 6];
        float4 n3 = xv[4 * c + 7];
        do_chunk(c, c0, c1, c2, c3);
        c0 = n0; c1 = n1; c2 = n2; c3 = n3;
    }
    do_chunk(NCHUNK - 1, c0, c1, c2, c3);
}

extern "C" void kernel_launch(void* const* d_in, const int* in_sizes, int n_in,
                              void* d_out, int out_size, void* d_ws, size_t ws_size,
                              hipStream_t stream) {
    const float* x   = (const float*)d_in[0];
    const float* Rp  = (const float*)d_in[1];
    const float* Cp  = (const float*)d_in[2];
    const float* nR  = (const float*)d_in[3];
    const float* nC  = (const float*)d_in[4];
    const float* muv = (const float*)d_in[5];
    const float* m0  = (const float*)d_in[6];
    float* out = (float*)d_out;

    dim3 grid(NB / BLOCK, N);   // (8, 32) = 256 blocks, one per CU
    lf_scan<<<grid, BLOCK, 0, stream>>>(x, Rp, Cp, nR, nC, muv, m0, out);
}

// Round 2
// 122.851 us; speedup vs baseline: 1.9285x; 1.9285x over previous
//
#include <hip/hip_runtime.h>
#include <math.h>

namespace {
constexpr int N  = 32;
constexpr int NB = 2048;
constexpr int T  = 1024;
constexpr float DT_  = 0.1f;
constexpr float RMIN = 1.0e5f, RMAX = 1.0e7f;
constexpr float CMIN = 1.0e-7f, CMAX = 1.0e-4f;
constexpr int BLOCK = 1024;          // 16 waves per block
constexpr int WPB   = BLOCK / 64;    // waves per block = 16
constexpr int SEG   = 256;           // timesteps per wave-iteration (64 lanes x 4)
constexpr int NSEG  = T / SEG;       // 4 serial segments per sequence
}

// One wave per (n, nb) sequence. Per 256-t segment:
//   - coalesced float4 load of x (1 KB / wave instruction)
//   - per-lane composition of 4 affine transforms (P,Q)
//   - 6-step shfl_up inclusive scan composing across 64 lanes
//   - exclusive shift -> per-lane entry state -> regenerate 4 outputs
//   - coalesced float4 store; carry m via lane-63 composite
__global__ void __launch_bounds__(BLOCK)
lf_scan(const float* __restrict__ x,
        const float* __restrict__ Rp,
        const float* __restrict__ Cp,
        const float* __restrict__ noise_R,
        const float* __restrict__ noise_C,
        const float* __restrict__ mu,
        const float* __restrict__ memory0,
        float* __restrict__ out)
{
    __shared__ __align__(16) float beta_s[T];
    const int tid = threadIdx.x;
    const int n   = blockIdx.y;

    // ---- beta for this n: exactly one element per thread ----
    {
        const float R_true = (RMAX - RMIN) / (1.0f + expf(-Rp[0])) + RMIN;
        const float C_true = (CMAX - CMIN) / (1.0f + expf(-Cp[0])) + CMIN;
        const int t   = tid;                 // BLOCK == T
        const int idx = t * N + n;           // (T, N, 1) layout
        const float rc = mu[idx] * (R_true * noise_R[idx]) * (C_true * noise_C[idx]);
        beta_s[t] = rc / (rc + DT_);
    }
    __syncthreads();

    const int w    = tid >> 6;
    const int lane = tid & 63;
    const int nb   = blockIdx.x * WPB + w;

    const size_t base = ((size_t)n * NB + (size_t)nb) * (size_t)T;
    const float4* __restrict__ xv = reinterpret_cast<const float4*>(x + base);
    float4*       __restrict__ ov = reinterpret_cast<float4*>(out + base);
    const float4* __restrict__ bv = reinterpret_cast<const float4*>(beta_s);

    float m = memory0[n * NB + nb];

    float4 xc = xv[lane];                    // prefetch segment 0
    for (int s = 0; s < NSEG; ++s) {
        float4 xn = xc;
        if (s + 1 < NSEG) xn = xv[(s + 1) * 64 + lane];   // prefetch next segment
        const float4 b = bv[s * 64 + lane];

        // per-lane composite of transforms t .. t+3 (increasing t):
        // f(m) = b*m + (1-b)*x ; compose: P *= b_i, Q = b_i*Q + (1-b_i)*x_i
        float P = b.x;
        float Q = (1.0f - b.x) * xc.x;
        Q = fmaf(b.y, Q, (1.0f - b.y) * xc.y); P *= b.y;
        Q = fmaf(b.z, Q, (1.0f - b.z) * xc.z); P *= b.z;
        Q = fmaf(b.w, Q, (1.0f - b.w) * xc.w); P *= b.w;

        // inclusive scan across 64 lanes (compose own AFTER incoming)
        #pragma unroll
        for (int d = 1; d < 64; d <<= 1) {
            const float Pin = __shfl_up(P, (unsigned)d, 64);
            const float Qin = __shfl_up(Q, (unsigned)d, 64);
            if (lane >= d) {
                Q = fmaf(P, Qin, Q);     // Q_new = P_own*Q_in + Q_own (uses pre-update P)
                P = P * Pin;
            }
        }

        // exclusive prefix for this lane's entry state
        float Pe = __shfl_up(P, 1u, 64);
        float Qe = __shfl_up(Q, 1u, 64);
        if (lane == 0) { Pe = 1.0f; Qe = 0.0f; }
        float me = fmaf(Pe, m, Qe);

        // regenerate 4 pre-update outputs serially within the lane
        float4 o;
        o.x = me; me = fmaf(b.x, me - xc.x, xc.x);
        o.y = me; me = fmaf(b.y, me - xc.y, xc.y);
        o.z = me; me = fmaf(b.z, me - xc.z, xc.z);
        o.w = me;                                 // 4th update folded into carry below
        ov[s * 64 + lane] = o;

        // segment carry from lane 63's inclusive composite
        const float P63 = __shfl(P, 63, 64);
        const float Q63 = __shfl(Q, 63, 64);
        m = fmaf(P63, m, Q63);

        xc = xn;
    }
}

extern "C" void kernel_launch(void* const* d_in, const int* in_sizes, int n_in,
                              void* d_out, int out_size, void* d_ws, size_t ws_size,
                              hipStream_t stream) {
    const float* x   = (const float*)d_in[0];
    const float* Rp  = (const float*)d_in[1];
    const float* Cp  = (const float*)d_in[2];
    const float* nR  = (const float*)d_in[3];
    const float* nC  = (const float*)d_in[4];
    const float* muv = (const float*)d_in[5];
    const float* m0  = (const float*)d_in[6];
    float* out = (float*)d_out;

    dim3 grid(NB / WPB, N);   // (128, 32) = 4096 blocks, 16 waves each
    lf_scan<<<grid, BLOCK, 0, stream>>>(x, Rp, Cp, nR, nC, muv, m0, out);
}

// Round 3
// 111.439 us; speedup vs baseline: 2.1260x; 1.1024x over previous
//
#include <hip/hip_runtime.h>
#include <math.h>

namespace {
constexpr int N  = 32;
constexpr int NB = 2048;
constexpr int T  = 1024;
constexpr float DT_  = 0.1f;
constexpr float RMIN = 1.0e5f, RMAX = 1.0e7f;
constexpr float CMIN = 1.0e-7f, CMAX = 1.0e-4f;
constexpr int BLOCK = 1024;          // 16 waves per block
constexpr int WPB   = BLOCK / 64;    // waves per block = 16
constexpr int NSEG  = 4;             // 4 x 256-timestep segments, scanned jointly
}

// Pass 1: beta once, transposed to [n][t] so the scan kernel reads it coalesced.
__global__ void __launch_bounds__(256)
beta_init(const float* __restrict__ Rp, const float* __restrict__ Cp,
          const float* __restrict__ noise_R, const float* __restrict__ noise_C,
          const float* __restrict__ mu, float* __restrict__ betaT)
{
    const int i = blockIdx.x * 256 + threadIdx.x;      // i = t*N + n
    const float R_true = (RMAX - RMIN) / (1.0f + expf(-Rp[0])) + RMIN;
    const float C_true = (CMAX - CMIN) / (1.0f + expf(-Cp[0])) + CMIN;
    const float rc = mu[i] * (R_true * noise_R[i]) * (C_true * noise_C[i]);
    const int t = i >> 5, n = i & (N - 1);
    betaT[n * T + t] = rc / (rc + DT_);
}

// Pass 2: one wave per (n, nb) sequence; 4 independent 64-lane affine scans
// interleaved for shuffle-latency hiding, then a 4-FMA carry chain.
__global__ void __launch_bounds__(BLOCK, 8)
lf_scan(const float* __restrict__ x,
        const float* __restrict__ betaT,
        const float* __restrict__ memory0,
        float* __restrict__ out)
{
    __shared__ __align__(16) float beta_s[T];
    const int tid = threadIdx.x;
    const int n   = blockIdx.y;

    beta_s[tid] = betaT[n * T + tid];                  // coalesced 4 KB, L2-hot
    __syncthreads();

    const int w    = tid >> 6;
    const int lane = tid & 63;
    const int nb   = blockIdx.x * WPB + w;

    const size_t base = ((size_t)n * NB + (size_t)nb) * (size_t)T;
    const float4* __restrict__ xv = reinterpret_cast<const float4*>(x + base);
    float4*       __restrict__ ov = reinterpret_cast<float4*>(out + base);
    const float4* __restrict__ bv = reinterpret_cast<const float4*>(beta_s);

    // ---- load full sequence slice: 4 segments x float4 ----
    float4 X[NSEG];
    #pragma unroll
    for (int s = 0; s < NSEG; ++s) X[s] = xv[s * 64 + lane];

    // ---- per-lane composition of 4 transforms per segment ----
    float P[NSEG], Q[NSEG];
    #pragma unroll
    for (int s = 0; s < NSEG; ++s) {
        const float4 b  = bv[s * 64 + lane];
        const float4 xc = X[s];
        float p = b.x, q = (1.0f - b.x) * xc.x;
        q = fmaf(b.y, q, (1.0f - b.y) * xc.y); p *= b.y;
        q = fmaf(b.z, q, (1.0f - b.z) * xc.z); p *= b.z;
        q = fmaf(b.w, q, (1.0f - b.w) * xc.w); p *= b.w;
        P[s] = p; Q[s] = q;
    }

    // ---- 4 independent 64-lane inclusive scans, shuffles interleaved ----
    #pragma unroll
    for (int d = 1; d < 64; d <<= 1) {
        float Pin[NSEG], Qin[NSEG];
        #pragma unroll
        for (int s = 0; s < NSEG; ++s) {
            Pin[s] = __shfl_up(P[s], (unsigned)d, 64);
            Qin[s] = __shfl_up(Q[s], (unsigned)d, 64);
        }
        #pragma unroll
        for (int s = 0; s < NSEG; ++s) {
            if (lane >= d) {
                Q[s] = fmaf(P[s], Qin[s], Q[s]);
                P[s] = P[s] * Pin[s];
            }
        }
    }

    // ---- per-segment: entry state, regen 4 pre-update outputs, carry ----
    float ms = memory0[n * NB + nb];
    #pragma unroll
    for (int s = 0; s < NSEG; ++s) {
        const float Pe  = __shfl_up(P[s], 1u, 64);
        const float Qe  = __shfl_up(Q[s], 1u, 64);
        const float P63 = __shfl(P[s], 63, 64);
        const float Q63 = __shfl(Q[s], 63, 64);
        float me = (lane == 0) ? ms : fmaf(Pe, ms, Qe);

        const float4 b  = bv[s * 64 + lane];
        const float4 xc = X[s];
        float4 o;
        o.x = me; me = fmaf(b.x, me - xc.x, xc.x);
        o.y = me; me = fmaf(b.y, me - xc.y, xc.y);
        o.z = me; me = fmaf(b.z, me - xc.z, xc.z);
        o.w = me;
        ov[s * 64 + lane] = o;

        ms = fmaf(P63, ms, Q63);                       // carry to next segment
    }
}

extern "C" void kernel_launch(void* const* d_in, const int* in_sizes, int n_in,
                              void* d_out, int out_size, void* d_ws, size_t ws_size,
                              hipStream_t stream) {
    const float* x   = (const float*)d_in[0];
    const float* Rp  = (const float*)d_in[1];
    const float* Cp  = (const float*)d_in[2];
    const float* nR  = (const float*)d_in[3];
    const float* nC  = (const float*)d_in[4];
    const float* muv = (const float*)d_in[5];
    const float* m0  = (const float*)d_in[6];
    float* out   = (float*)d_out;
    float* betaT = (float*)d_ws;                       // T*N floats = 128 KB

    beta_init<<<dim3((T * N) / 256), 256, 0, stream>>>(Rp, Cp, nR, nC, muv, betaT);
    dim3 grid(NB / WPB, N);                            // (128, 32)
    lf_scan<<<grid, BLOCK, 0, stream>>>(x, betaT, m0, out);
}

// Round 5
// 96.008 us; speedup vs baseline: 2.4677x; 1.1607x over previous
//
#include <hip/hip_runtime.h>
#include <math.h>

namespace {
constexpr int N  = 32;
constexpr int NB = 2048;
constexpr int T  = 1024;
constexpr float DT_  = 0.1f;
constexpr float RMIN = 1.0e5f, RMAX = 1.0e7f;
constexpr float CMIN = 1.0e-7f, CMAX = 1.0e-4f;
constexpr int NSEG = 4;              // 4 x 256-timestep segments per wave

typedef float f4 __attribute__((ext_vector_type(4)));   // native vector for nt builtins
}

// Pass 1: beta once, transposed to [n][t] (128 KB, stays L2-resident).
__global__ void __launch_bounds__(256)
beta_init(const float* __restrict__ Rp, const float* __restrict__ Cp,
          const float* __restrict__ noise_R, const float* __restrict__ noise_C,
          const float* __restrict__ mu, float* __restrict__ betaT)
{
    const int i = blockIdx.x * 256 + threadIdx.x;      // i = t*N + n
    const float R_true = (RMAX - RMIN) / (1.0f + expf(-Rp[0])) + RMIN;
    const float C_true = (CMAX - CMIN) / (1.0f + expf(-Cp[0])) + CMIN;
    const float rc = mu[i] * (R_true * noise_R[i]) * (C_true * noise_C[i]);
    const int t = i >> 5, n = i & (N - 1);
    betaT[n * T + t] = rc / (rc + DT_);
}

// Pass 2: one wave per (n, nb) sequence. No LDS, no barrier: beta comes
// straight from L2. Streaming x/out use nontemporal loads/stores.
__global__ void __launch_bounds__(256, 8)
lf_scan(const float* __restrict__ x,
        const float* __restrict__ betaT,
        const float* __restrict__ memory0,
        float* __restrict__ out)
{
    const int tid  = threadIdx.x;
    const int w    = tid >> 6;
    const int lane = tid & 63;
    const int bid  = blockIdx.x;
    const int n    = bid >> 9;                          // 512 blocks per n
    const int nb   = ((bid & 511) << 2) + w;            // 4 waves per block

    const size_t base = ((size_t)n * NB + (size_t)nb) * (size_t)T;
    const f4* __restrict__ xv = reinterpret_cast<const f4*>(x + base);
    f4*       __restrict__ ov = reinterpret_cast<f4*>(out + base);
    const f4* __restrict__ bv = reinterpret_cast<const f4*>(betaT + n * T);

    // ---- issue all loads up front: x nontemporal (HBM), beta cached (L2) ----
    f4 X[NSEG], B[NSEG];
    #pragma unroll
    for (int s = 0; s < NSEG; ++s) X[s] = __builtin_nontemporal_load(&xv[s * 64 + lane]);
    #pragma unroll
    for (int s = 0; s < NSEG; ++s) B[s] = bv[s * 64 + lane];

    // ---- per-lane composition of 4 transforms per segment ----
    float P[NSEG], Q[NSEG];
    #pragma unroll
    for (int s = 0; s < NSEG; ++s) {
        const f4 b  = B[s];
        const f4 xc = X[s];
        float p = b.x, q = (1.0f - b.x) * xc.x;
        q = fmaf(b.y, q, (1.0f - b.y) * xc.y); p *= b.y;
        q = fmaf(b.z, q, (1.0f - b.z) * xc.z); p *= b.z;
        q = fmaf(b.w, q, (1.0f - b.w) * xc.w); p *= b.w;
        P[s] = p; Q[s] = q;
    }

    // ---- 4 independent 64-lane inclusive scans, shuffles interleaved ----
    #pragma unroll
    for (int d = 1; d < 64; d <<= 1) {
        float Pin[NSEG], Qin[NSEG];
        #pragma unroll
        for (int s = 0; s < NSEG; ++s) {
            Pin[s] = __shfl_up(P[s], (unsigned)d, 64);
            Qin[s] = __shfl_up(Q[s], (unsigned)d, 64);
        }
        #pragma unroll
        for (int s = 0; s < NSEG; ++s) {
            if (lane >= d) {
                Q[s] = fmaf(P[s], Qin[s], Q[s]);
                P[s] = P[s] * Pin[s];
            }
        }
    }

    // ---- per-segment: entry state, regen 4 pre-update outputs, carry ----
    float ms = memory0[n * NB + nb];
    #pragma unroll
    for (int s = 0; s < NSEG; ++s) {
        const float Pe  = __shfl_up(P[s], 1u, 64);
        const float Qe  = __shfl_up(Q[s], 1u, 64);
        const float P63 = __shfl(P[s], 63, 64);
        const float Q63 = __shfl(Q[s], 63, 64);
        float me = (lane == 0) ? ms : fmaf(Pe, ms, Qe);

        const f4 b  = B[s];
        const f4 xc = X[s];
        f4 o;
        o.x = me; me = fmaf(b.x, me - xc.x, xc.x);
        o.y = me; me = fmaf(b.y, me - xc.y, xc.y);
        o.z = me; me = fmaf(b.z, me - xc.z, xc.z);
        o.w = me;
        __builtin_nontemporal_store(o, &ov[s * 64 + lane]);

        ms = fmaf(P63, ms, Q63);                        // carry to next segment
    }
}

extern "C" void kernel_launch(void* const* d_in, const int* in_sizes, int n_in,
                              void* d_out, int out_size, void* d_ws, size_t ws_size,
                              hipStream_t stream) {
    const float* x   = (const float*)d_in[0];
    const float* Rp  = (const float*)d_in[1];
    const float* Cp  = (const float*)d_in[2];
    const float* nR  = (const float*)d_in[3];
    const float* nC  = (const float*)d_in[4];
    const float* muv = (const float*)d_in[5];
    const float* m0  = (const float*)d_in[6];
    float* out   = (float*)d_out;
    float* betaT = (float*)d_ws;                        // T*N floats = 128 KB

    beta_init<<<dim3((T * N) / 256), 256, 0, stream>>>(Rp, Cp, nR, nC, muv, betaT);
    lf_scan<<<dim3(N * (NB / 4)), 256, 0, stream>>>(x, betaT, m0, out);
}